// Round 1
// 567.340 us; speedup vs baseline: 1.1232x; 1.1232x over previous
//
#include <hip/hip_runtime.h>
#include <math.h>

// KGATConv: N=50000, E=800000, D=64, R=16, fp32.
// R7: k_att restructured to 8-threads/edge (wave-coalesced proj-row gathers,
// 8 concurrent 128B requests per VMEM instr) + nontemporal efeat stream
// (preserve L3 residency of proj). k_aggB inner broadcast loop unrolled x4
// (4 outstanding nfeat gathers, dual accumulators). k_proj loops relations
// in-block (A-tile + fragments loaded once).

#define DIM 64
#define PA 72

typedef _Float16 half8 __attribute__((ext_vector_type(8)));
typedef float f32x4 __attribute__((ext_vector_type(4)));
typedef unsigned int u32x4 __attribute__((ext_vector_type(4)));

__device__ __forceinline__ float4 f4zero() { return make_float4(0.f, 0.f, 0.f, 0.f); }

__device__ __forceinline__ unsigned short f2bf(float x) {
    unsigned u = __float_as_uint(x);
    u += 0x7FFFu + ((u >> 16) & 1u);   // RNE
    return (unsigned short)(u >> 16);
}

__device__ __forceinline__ float fast_tanh(float x) {
    float ex = __expf(2.0f * x);
    return 1.0f - 2.0f / (ex + 1.0f);
}

// unpack 8 bf16 (in a u32x4) to fp32
__device__ __forceinline__ void bf8up(u32x4 u, float* f) {
    f[0] = __uint_as_float(u[0] << 16);
    f[1] = __uint_as_float(u[0] & 0xFFFF0000u);
    f[2] = __uint_as_float(u[1] << 16);
    f[3] = __uint_as_float(u[1] & 0xFFFF0000u);
    f[4] = __uint_as_float(u[2] << 16);
    f[5] = __uint_as_float(u[2] & 0xFFFF0000u);
    f[6] = __uint_as_float(u[3] << 16);
    f[7] = __uint_as_float(u[3] & 0xFFFF0000u);
}

// ---------------------------------------------------------------------------
// proj[r,n,:] = bf16( nfeat[n,:] @ relW[r,:,:] ) via mfma_f32_16x16x32_f16
// A-tile (64 nodes) + A-fragments loaded once; loop over all R relations.
// ---------------------------------------------------------------------------
__global__ __launch_bounds__(256) void k_proj(const float* __restrict__ nfeat,
                                              const float* __restrict__ relW,
                                              unsigned short* __restrict__ proj,
                                              int N, int R) {
    __shared__ _Float16 shA[64 * PA];
    __shared__ _Float16 shB[64 * PA];

    const int tx = threadIdx.x;
    const int n0 = blockIdx.x * 64;

    const float4* nf4 = (const float4*)(nfeat + (size_t)n0 * DIM);
#pragma unroll
    for (int i = 0; i < 4; ++i) {
        int idx = tx + 256 * i;
        int row = idx >> 4, c = idx & 15;
        float4 v = (n0 + row < N) ? nf4[idx] : f4zero();
        _Float16* p = &shA[row * PA + c * 4];
        p[0] = (_Float16)v.x; p[1] = (_Float16)v.y;
        p[2] = (_Float16)v.z; p[3] = (_Float16)v.w;
    }
    __syncthreads();

    const int w = tx >> 6;
    const int lane = tx & 63;
    const int lm = lane & 15;
    const int lq = lane >> 4;
    const int m0 = w * 16;

    // A fragments are relation-independent: load once.
    half8 a0 = *(const half8*)&shA[(m0 + lm) * PA + 0 * 32 + lq * 8];
    half8 a1 = *(const half8*)&shA[(m0 + lm) * PA + 1 * 32 + lq * 8];

    for (int r = 0; r < R; ++r) {
        __syncthreads();   // previous iteration's shB reads complete
        const float4* Wr4 = (const float4*)(relW + (size_t)r * DIM * DIM);
#pragma unroll
        for (int i = 0; i < 4; ++i) {
            int idx = tx + 256 * i;
            int d = idx >> 4, c = (idx & 15) * 4;
            float4 v = Wr4[idx];
            shB[(c + 0) * PA + d] = (_Float16)v.x;
            shB[(c + 1) * PA + d] = (_Float16)v.y;
            shB[(c + 2) * PA + d] = (_Float16)v.z;
            shB[(c + 3) * PA + d] = (_Float16)v.w;
        }
        __syncthreads();

        f32x4 acc[4];
#pragma unroll
        for (int ct = 0; ct < 4; ++ct) {
            half8 b0 = *(const half8*)&shB[(ct * 16 + lm) * PA + 0 * 32 + lq * 8];
            half8 b1 = *(const half8*)&shB[(ct * 16 + lm) * PA + 1 * 32 + lq * 8];
            f32x4 c = {0.f, 0.f, 0.f, 0.f};
            c = __builtin_amdgcn_mfma_f32_16x16x32_f16(a0, b0, c, 0, 0, 0);
            c = __builtin_amdgcn_mfma_f32_16x16x32_f16(a1, b1, c, 0, 0, 0);
            acc[ct] = c;
        }

        unsigned short* projR = proj + ((size_t)r * N + n0) * DIM;
#pragma unroll
        for (int ct = 0; ct < 4; ++ct) {
#pragma unroll
            for (int i = 0; i < 4; ++i) {
                int row = m0 + lq * 4 + i;
                int col = ct * 16 + lm;
                if (n0 + row < N)
                    projR[(size_t)row * DIM + col] = f2bf(acc[ct][i]);
            }
        }
    }
}

// ---------------------------------------------------------------------------
// CSR build: histogram -> 3-kernel coalesced scan -> fill (pos + sorted src)
// ---------------------------------------------------------------------------
__global__ __launch_bounds__(256) void k_hist(const int* __restrict__ dst,
                                              int* __restrict__ deg, int E) {
    int e = blockIdx.x * 256 + threadIdx.x;
    if (e < E) atomicAdd(&deg[dst[e]], 1);
}

__global__ __launch_bounds__(256) void k_scan1(const int* __restrict__ deg,
                                               int* __restrict__ bsum, int N) {
    __shared__ int sh[256];
    int i = blockIdx.x * 256 + threadIdx.x;
    int t = threadIdx.x;
    sh[t] = (i < N) ? deg[i] : 0;
    __syncthreads();
#pragma unroll
    for (int s = 128; s > 0; s >>= 1) {
        if (t < s) sh[t] += sh[t + s];
        __syncthreads();
    }
    if (t == 0) bsum[blockIdx.x] = sh[0];
}

__global__ __launch_bounds__(256) void k_scan2(int* __restrict__ bsum, int nb,
                                               int* __restrict__ offN, int E) {
    __shared__ int sh[256];
    int t = threadIdx.x;
    int v = (t < nb) ? bsum[t] : 0;
    sh[t] = v;
    __syncthreads();
#pragma unroll
    for (int d = 1; d < 256; d <<= 1) {
        int o = (t >= d) ? sh[t - d] : 0;
        __syncthreads();
        sh[t] += o;
        __syncthreads();
    }
    if (t < nb) bsum[t] = sh[t] - v;   // exclusive block prefix
    if (t == 0) offN[0] = E;           // off[N] = E
}

__global__ __launch_bounds__(256) void k_scan3(const int* __restrict__ deg,
                                               const int* __restrict__ bsum,
                                               int* __restrict__ off,
                                               int* __restrict__ cursor, int N) {
    __shared__ int sh[256];
    int i = blockIdx.x * 256 + threadIdx.x;
    int t = threadIdx.x;
    int v = (i < N) ? deg[i] : 0;
    sh[t] = v;
    __syncthreads();
#pragma unroll
    for (int d = 1; d < 256; d <<= 1) {
        int o = (t >= d) ? sh[t - d] : 0;
        __syncthreads();
        sh[t] += o;
        __syncthreads();
    }
    if (i < N) {
        int pre = bsum[blockIdx.x] + sh[t] - v;   // exclusive global prefix
        off[i] = pre;
        cursor[i] = pre;
    }
}

__global__ __launch_bounds__(256) void k_fill(const int* __restrict__ dst,
                                              const int* __restrict__ src,
                                              int* __restrict__ cursor,
                                              int* __restrict__ pos,
                                              int* __restrict__ src_s, int E) {
    int e = blockIdx.x * 256 + threadIdx.x;
    if (e >= E) return;
    int p = atomicAdd(&cursor[dst[e]], 1);
    pos[e] = p;
    src_s[p] = src[e];
}

// ---------------------------------------------------------------------------
// Attention, 8 threads per edge: sub-lane owns 8 dims (16B of each proj row).
// A wave's single dwordx4 instruction touches 8 distinct proj rows -> 8
// concurrent 128B gather requests. efeat is streamed non-temporally so the
// one-shot 205MB stream does not evict the 102MB proj table from L3.
// ---------------------------------------------------------------------------
__global__ __launch_bounds__(256) void k_att(const unsigned short* __restrict__ proj,
                                             const float* __restrict__ efeat,
                                             const int* __restrict__ src,
                                             const int* __restrict__ dst,
                                             const int* __restrict__ etype,
                                             const int* __restrict__ pos,
                                             float* __restrict__ att_s,
                                             int N, int E) {
    int t = blockIdx.x * 256 + threadIdx.x;
    int e = t >> 3;
    int sub = t & 7;
    if (e >= E) return;
    int s = src[e], d = dst[e], r = etype[e];

    const u32x4* tp = (const u32x4*)(proj + ((size_t)((unsigned)(r * N + s))) * DIM) + sub;
    const u32x4* hp = (const u32x4*)(proj + ((size_t)((unsigned)(r * N + d))) * DIM) + sub;
    const f32x4* ef = (const f32x4*)(efeat + (size_t)e * DIM) + sub * 2;

    u32x4 tu = *tp;
    u32x4 hu = *hp;
    f32x4 efa = __builtin_nontemporal_load(ef);
    f32x4 efb = __builtin_nontemporal_load(ef + 1);

    float tf[8], hf[8];
    bf8up(tu, tf);
    bf8up(hu, hf);
    float ev[8] = {efa[0], efa[1], efa[2], efa[3], efb[0], efb[1], efb[2], efb[3]};

    float dotv = 0.f;
#pragma unroll
    for (int i = 0; i < 8; ++i)
        dotv = fmaf(tf[i], fast_tanh(hf[i] + ev[i]), dotv);

    // reduce across the 8-lane group
    dotv += __shfl_xor(dotv, 1);
    dotv += __shfl_xor(dotv, 2);
    dotv += __shfl_xor(dotv, 4);

    if (sub == 0) att_s[pos[e]] = dotv;
}

// ---------------------------------------------------------------------------
// Per-node softmax + aggregation + bi-interaction. Wave per node; segment
// processed edge-parallel (coalesced att_s/src_s), exact wave max, then
// shuffle-broadcast + 4-deep unrolled independent nfeat gathers.
// ---------------------------------------------------------------------------
__global__ __launch_bounds__(256) void k_aggB(const float* __restrict__ att_s,
                                              const int* __restrict__ src_s,
                                              const float* __restrict__ nfeat,
                                              const int* __restrict__ off,
                                              const float* __restrict__ W1,
                                              const float* __restrict__ W2,
                                              float* __restrict__ hn,
                                              float* __restrict__ out,
                                              int N) {
    const int node = blockIdx.x * 4 + (threadIdx.x >> 6);
    if (node >= N) return;
    const int lane = threadIdx.x & 63;

    const int jb = off[node];
    const int je = off[node + 1];

    // exact segment max (edge-parallel, coalesced)
    float m = -INFINITY;
    for (int j0 = jb; j0 < je; j0 += 64) {
        int j = j0 + lane;
        float a = (j < je) ? att_s[j] : -INFINITY;
        m = fmaxf(m, a);
    }
#pragma unroll
    for (int ms = 32; ms; ms >>= 1) m = fmaxf(m, __shfl_xor(m, ms));

    float pl = 0.f, acc = 0.f, acc2 = 0.f;
    for (int j0 = jb; j0 < je; j0 += 64) {
        int j = j0 + lane;
        int cnt = min(64, je - j0);
        float a = (j < je) ? att_s[j] : -INFINITY;
        float p = __expf(a - m);          // inactive lanes: exp(-inf)=0
        int s = (j < je) ? src_s[j] : 0;
        pl += p;
        int jj = 0;
        for (; jj + 3 < cnt; jj += 4) {   // 4 outstanding gathers
            float pj0 = __shfl(p, jj + 0);
            float pj1 = __shfl(p, jj + 1);
            float pj2 = __shfl(p, jj + 2);
            float pj3 = __shfl(p, jj + 3);
            int sj0 = __shfl(s, jj + 0);
            int sj1 = __shfl(s, jj + 1);
            int sj2 = __shfl(s, jj + 2);
            int sj3 = __shfl(s, jj + 3);
            float x0 = nfeat[(size_t)sj0 * DIM + lane];
            float x1 = nfeat[(size_t)sj1 * DIM + lane];
            float x2 = nfeat[(size_t)sj2 * DIM + lane];
            float x3 = nfeat[(size_t)sj3 * DIM + lane];
            acc  = fmaf(pj0, x0, acc);
            acc2 = fmaf(pj1, x1, acc2);
            acc  = fmaf(pj2, x2, acc);
            acc2 = fmaf(pj3, x3, acc2);
        }
        for (; jj < cnt; ++jj) {
            float pj = __shfl(p, jj);
            int sj = __shfl(s, jj);
            acc = fmaf(pj, nfeat[(size_t)sj * DIM + lane], acc);
        }
    }
    acc += acc2;
#pragma unroll
    for (int ms = 32; ms; ms >>= 1) pl += __shfl_xor(pl, ms);

    const float hval = (je > jb) ? acc / pl : 0.f;
    hn[(size_t)node * DIM + lane] = hval;

    const float nf = nfeat[(size_t)node * DIM + lane];
    const float v1 = nf + hval;
    const float v2 = nf * hval;
    float o1 = 0.f, o2 = 0.f;
#pragma unroll 8
    for (int d = 0; d < DIM; ++d) {
        float s1 = __shfl(v1, d);
        float s2 = __shfl(v2, d);
        o1 = fmaf(s1, W1[d * DIM + lane], o1);
        o2 = fmaf(s2, W2[d * DIM + lane], o2);
    }
    out[(size_t)node * DIM + lane] =
        (o1 >= 0.f ? o1 : 0.01f * o1) + (o2 >= 0.f ? o2 : 0.01f * o2);
}

extern "C" void kernel_launch(void* const* d_in, const int* in_sizes, int n_in,
                              void* d_out, int out_size, void* d_ws, size_t ws_size,
                              hipStream_t stream) {
    const float* nfeat = (const float*)d_in[0];
    const float* efeat = (const float*)d_in[1];
    const float* relW  = (const float*)d_in[2];
    const float* W1    = (const float*)d_in[3];
    const float* W2    = (const float*)d_in[4];
    const int* src   = (const int*)d_in[5];
    const int* dst   = (const int*)d_in[6];
    const int* etype = (const int*)d_in[7];

    const int N = in_sizes[0] / DIM;
    const int E = in_sizes[5];
    const int R = in_sizes[2] / (DIM * DIM);
    const int NB = (N + 255) / 256;   // scan blocks (<=256)

    float* out = (float*)d_out;
    float* hn  = out;
    float* bi  = out + (size_t)N * DIM;

    // ws: proj bf16 | deg[N] | off[N+1] | cursor[N] | bsum[256] | pos[E] | src_s[E] | att_s[E]
    unsigned short* proj = (unsigned short*)d_ws;
    size_t projElems = (size_t)R * N * DIM;
    int* deg    = (int*)(proj + projElems);
    int* off    = deg + N;
    int* cursor = off + (N + 1);
    int* bsum   = cursor + N;
    int* pos    = bsum + 256;
    int* src_s  = pos + E;
    float* att_s = (float*)(src_s + E);

    (void)hipMemsetAsync(deg, 0, (size_t)N * sizeof(int), stream);

    k_hist<<<(E + 255) / 256, 256, 0, stream>>>(dst, deg, E);
    k_scan1<<<NB, 256, 0, stream>>>(deg, bsum, N);
    k_scan2<<<1, 256, 0, stream>>>(bsum, NB, off + N, E);
    k_scan3<<<NB, 256, 0, stream>>>(deg, bsum, off, cursor, N);
    k_fill<<<(E + 255) / 256, 256, 0, stream>>>(dst, src, cursor, pos, src_s, E);

    k_proj<<<(N + 63) / 64, 256, 0, stream>>>(nfeat, relW, proj, N, R);

    k_att<<<((size_t)E * 8 + 255) / 256, 256, 0, stream>>>(proj, efeat, src, dst, etype,
                                                           pos, att_s, N, E);

    k_aggB<<<(N + 3) / 4, 256, 0, stream>>>(att_s, src_s, nfeat, off,
                                            W1, W2, hn, bi, N);
}